// Round 10
// baseline (541.432 us; speedup 1.0000x reference)
//
#include <hip/hip_runtime.h>
#include <hip/hip_bf16.h>

#define DOUT 128
#define DIN  256
#define BROWS 64            // rows per bucket
#define MAXNB 1024          // bucket-scan width cap (nb = ceil(N/64) = 782)
#define BIN_CHUNK 4096      // edges per bin_edges block
#define SCHUNK 9216         // edges per spmm LDS chunk (mean 8184 + 11 sigma)
#define NREG 4              // hV row regions (3.2 MB each -> per-XCD L2)
#define SBINS (NREG * BROWS)

typedef __attribute__((ext_vector_type(8))) short bf16x8;
typedef __attribute__((ext_vector_type(4))) float f32x4;
union FragU { uint4 q; bf16x8 f; };

static __device__ __forceinline__ float bf16lo_to_f(unsigned u) {
    return __uint_as_float(u << 16);
}
static __device__ __forceinline__ float bf16hi_to_f(unsigned u) {
    return __uint_as_float(u & 0xffff0000u);
}
static __device__ __forceinline__ unsigned f_to_bf16_bits(float f) {
    unsigned u = __float_as_uint(f);               // RNE round to bf16
    return (u + 0x7fffu + ((u >> 16) & 1u)) >> 16;
}
static __device__ __forceinline__ unsigned pack2(float a, float b) {
    return f_to_bf16_bits(a) | (f_to_bf16_bits(b) << 16);
}

// ========== tiny: W^T, V^T -> bf16 (done once, 96 KB total) ================
__global__ __launch_bounds__(256) void conv_wv(const float* __restrict__ W,
                                               const float* __restrict__ V,
                                               unsigned short* __restrict__ WT,
                                               unsigned short* __restrict__ VT) {
    int n = blockIdx.x;                 // 0..127 output row (= col of W/V)
    int t = threadIdx.x;                // 0..255
    WT[n * 256 + t] = (unsigned short)f_to_bf16_bits(W[t * DOUT + n]);
    if (t < 128) VT[n * 128 + t] = (unsigned short)f_to_bf16_bits(V[t * DOUT + n]);
}

// ======================= hV = h @ V via MFMA (validated r5) ================
__global__ __launch_bounds__(256) void hv_gemm(const float* __restrict__ h,
                                               const unsigned* __restrict__ VTu,
                                               unsigned short* __restrict__ hV,
                                               int N) {
    __shared__ unsigned xs[64 * 20];
    int t = threadIdx.x;
    int r0 = blockIdx.x * 64;
    int w = t >> 6, l = t & 63;
    int wm = w >> 1, wn = w & 1;
    int lm = l & 15, lk = l >> 4;
    f32x4 acc[2][4];
#pragma unroll
    for (int i = 0; i < 2; ++i)
#pragma unroll
        for (int j = 0; j < 4; ++j) acc[i][j] = (f32x4){0.f, 0.f, 0.f, 0.f};

    int srow = min(r0 + (t >> 2), N - 1);
    const float* hrow = h + (size_t)srow * DOUT + (t & 3) * 8;
    unsigned* xsw = &xs[(t >> 2) * 20 + (t & 3) * 4];

    for (int k0 = 0; k0 < DOUT; k0 += 32) {
        float4 f0 = *(const float4*)(hrow + k0);
        float4 f1 = *(const float4*)(hrow + k0 + 4);
        ((uint4*)xsw)[0] = make_uint4(pack2(f0.x, f0.y), pack2(f0.z, f0.w),
                                      pack2(f1.x, f1.y), pack2(f1.z, f1.w));
        __syncthreads();
        FragU a[2], b[4];
#pragma unroll
        for (int i = 0; i < 2; ++i)
            a[i].q = *(const uint4*)&xs[(wm * 32 + i * 16 + lm) * 20 + lk * 4];
#pragma unroll
        for (int j = 0; j < 4; ++j)
            b[j].q = *(const uint4*)(VTu + (size_t)(wn * 64 + j * 16 + lm) * 64 +
                                     (k0 >> 1) + lk * 4);
#pragma unroll
        for (int i = 0; i < 2; ++i)
#pragma unroll
            for (int j = 0; j < 4; ++j)
                acc[i][j] = __builtin_amdgcn_mfma_f32_16x16x32_bf16(
                    a[i].f, b[j].f, acc[i][j], 0, 0, 0);
        __syncthreads();
    }
#pragma unroll
    for (int i = 0; i < 2; ++i)
#pragma unroll
        for (int j = 0; j < 4; ++j) {
            int gr0 = r0 + wm * 32 + i * 16 + lk * 4;
            int gc = wn * 64 + j * 16 + lm;
#pragma unroll
            for (int r = 0; r < 4; ++r) {
                int gr = gr0 + r;
                if (gr < N)
                    hV[(size_t)gr * DOUT + gc] =
                        (unsigned short)f_to_bf16_bits(acc[i][j][r]);
            }
        }
}

// ======================= bucket histogram (validated r5) ===================
__global__ void bucket_hist(const int* __restrict__ rows, int* __restrict__ gcnt,
                            int nE, int nb) {
    __shared__ int hc[MAXNB];
    for (int i = threadIdx.x; i < nb; i += blockDim.x) hc[i] = 0;
    __syncthreads();
    for (int i = blockIdx.x * blockDim.x + threadIdx.x; i < nE;
         i += gridDim.x * blockDim.x)
        atomicAdd(&hc[rows[i] / BROWS], 1);
    __syncthreads();
    for (int i = threadIdx.x; i < nb; i += blockDim.x)
        if (hc[i]) atomicAdd(&gcnt[i], hc[i]);
}

// ============ exclusive scan of bucket counts (shfl-scan r6) ===============
__global__ __launch_bounds__(1024) void scan_buckets(const int* __restrict__ gcnt,
                                                     int* __restrict__ bptr,
                                                     int* __restrict__ gcur, int nb) {
    __shared__ int wtot[16];
    int t = threadIdx.x;
    int c = (t < nb) ? gcnt[t] : 0;
    int v = c;
#pragma unroll
    for (int d = 1; d < 64; d <<= 1) {
        int u = __shfl_up(v, d);
        if ((t & 63) >= d) v += u;
    }
    if ((t & 63) == 63) wtot[t >> 6] = v;
    __syncthreads();
    if (t < 16) {
        int wv = wtot[t];
#pragma unroll
        for (int d = 1; d < 16; d <<= 1) {
            int u = __shfl_up(wv, d);
            if (t >= d) wv += u;
        }
        wtot[t] = wv;
    }
    __syncthreads();
    int incl = v + ((t >= 64) ? wtot[(t >> 6) - 1] : 0);
    if (t == 0) bptr[0] = 0;
    if (t < nb) { bptr[t + 1] = incl; gcur[t] = incl - c; }
}

// ===== bin edges into bucket-major order (shfl-scan r6) ====================
// erow byte carries (col_region<<6) | local_row (validated r7).
__global__ __launch_bounds__(1024) void bin_edges(const int* __restrict__ rows,
                                                  const int* __restrict__ cols,
                                                  const float* __restrict__ vals,
                                                  int* __restrict__ gcur,
                                                  unsigned* __restrict__ ecv4,
                                                  unsigned char* __restrict__ erow,
                                                  int nE, int nb, float regInv) {
    __shared__ unsigned secv[BIN_CHUNK];                   // 16 KB
    __shared__ unsigned short srow16[BIN_CHUNK];           // 8 KB
    __shared__ unsigned char sreg[BIN_CHUNK];              // 4 KB
    __shared__ int hcnt[MAXNB], loff[MAXNB], lcur[MAXNB], gbase[MAXNB];
    __shared__ int wtot[16];
    int t = threadIdx.x;
    int base = blockIdx.x * BIN_CHUNK;
    int nvalid = min(BIN_CHUNK, nE - base);
    hcnt[t] = 0;
    __syncthreads();
    for (int j = t; j < nvalid; j += 1024)            // A: local hist
        atomicAdd(&hcnt[rows[base + j] / BROWS], 1);
    __syncthreads();
    int myc = hcnt[t];                                 // B: hierarchical scan
    int v = myc;
#pragma unroll
    for (int d = 1; d < 64; d <<= 1) {
        int u = __shfl_up(v, d);
        if ((t & 63) >= d) v += u;
    }
    if ((t & 63) == 63) wtot[t >> 6] = v;
    __syncthreads();
    if (t < 16) {
        int wv = wtot[t];
#pragma unroll
        for (int d = 1; d < 16; d <<= 1) {
            int u = __shfl_up(wv, d);
            if (t >= d) wv += u;
        }
        wtot[t] = wv;
    }
    __syncthreads();
    int excl = v - myc + ((t >= 64) ? wtot[(t >> 6) - 1] : 0);
    loff[t] = excl;
    lcur[t] = excl;
    if (t < nb && myc > 0) gbase[t] = atomicAdd(&gcur[t], myc);  // C: reserve
    __syncthreads();
    for (int j = t; j < nvalid; j += 1024) {          // D: place into LDS
        int i = base + j;
        unsigned r = (unsigned)rows[i];
        int col = cols[i];
        int bk = (int)r / BROWS;
        int reg = min(NREG - 1, (int)((float)col * regInv));
        int slot = atomicAdd(&lcur[bk], 1);
        secv[slot] = ((unsigned)col << 16) | f_to_bf16_bits(vals[i]);
        srow16[slot] = (unsigned short)r;
        sreg[slot] = (unsigned char)reg;
    }
    __syncthreads();
    for (int j = t; j < nvalid; j += 1024) {          // E: coalesced write-out
        unsigned r = srow16[j];
        int bk = (int)r / BROWS;
        int dst = gbase[bk] + (j - loff[bk]);
        ecv4[dst] = secv[j];
        erow[dst] = (unsigned char)((sreg[j] << 6) | (r & (BROWS - 1)));
    }
}

// ========= SPMM + fused epilogue, r10: r7 phases + 8-deep MLP, lean code ===
// r7 structure (256-bin sort, 4 L2-slab phases; fetch 157 MB validated).
// Walk unrolled 2 groups/iter (8 gathers in flight, dual accumulators) but
// with `#pragma unroll 1` on the phase and row loops so the big body is
// emitted ONCE (r8's 32x replication suspected of killing the toolchain).
__global__ __launch_bounds__(512) void spmm_epi(const int* __restrict__ bptr,
                                                const unsigned* __restrict__ ecv4,
                                                const unsigned char* __restrict__ erow,
                                                const unsigned* __restrict__ hV,
                                                const float* __restrict__ x,
                                                const unsigned* __restrict__ WTu,
                                                float* __restrict__ out, int N) {
    __shared__ __align__(16) unsigned srec[SCHUNK + SBINS * 8];  // 45056 B
    __shared__ int rcnt[SBINS], rptr[SBINS + 1], rcur[SBINS];
    int t = threadIdx.x;
    int b = blockIdx.x;
    int wave = t >> 6, lane = t & 63;
    int hf = lane >> 5;                                // half index 0/1
    int cl = lane & 31;                                // col block: 4*cl..4*cl+3
    int beg = bptr[b], end = bptr[b + 1];
    const uint2* hv2cl = (const uint2*)hV + cl;        // row stride = 32 uint2

    float4 acc[8];
#pragma unroll
    for (int j = 0; j < 8; ++j) acc[j] = make_float4(0.f, 0.f, 0.f, 0.f);

    for (int cb = beg; cb < end; cb += SCHUNK) {
        int nval = min(SCHUNK, end - cb);
        if (t < SBINS) rcnt[t] = 0;
        __syncthreads();
        for (int j = t; j < nval; j += 512)            // hist by (reg,row) bin
            atomicAdd(&rcnt[erow[cb + j]], 1);
        __syncthreads();
        if (wave == 0) {                               // 256-bin scan, 4/lane
            int b0 = 4 * lane;
            int c0 = (rcnt[b0] + 7) & ~7;
            int c1 = (rcnt[b0 + 1] + 7) & ~7;
            int c2 = (rcnt[b0 + 2] + 7) & ~7;
            int c3 = (rcnt[b0 + 3] + 7) & ~7;
            int s1 = c0 + c1, s2 = s1 + c2, tot = s2 + c3;
            int v = tot;
#pragma unroll
            for (int d = 1; d < 64; d <<= 1) {
                int u = __shfl_up(v, d);
                if (lane >= d) v += u;
            }
            int base0 = v - tot;
            rptr[b0 + 1] = base0 + c0;
            rptr[b0 + 2] = base0 + s1;
            rptr[b0 + 3] = base0 + s2;
            rptr[b0 + 4] = base0 + tot;
            rcur[b0]     = base0;
            rcur[b0 + 1] = base0 + c0;
            rcur[b0 + 2] = base0 + s1;
            rcur[b0 + 3] = base0 + s2;
            if (lane == 0) rptr[0] = 0;
        }
        __syncthreads();
        for (int j = t; j < nval; j += 512) {          // place sorted-by-bin
            int bin = erow[cb + j];
            int slot = atomicAdd(&rcur[bin], 1);
            srec[slot] = ecv4[cb + j];
        }
        __syncthreads();
        if (t < SBINS) {                               // zero-fill pad slots
            int e0 = rcur[t];
            int e1 = rptr[t + 1];
            for (int k = e0; k < e1; ++k) srec[k] = 0u;
        }
        __syncthreads();
#pragma unroll 1
        for (int p = 0; p < NREG; ++p) {               // L2-slab phases
#pragma unroll 1
            for (int rr = 0; rr < 8; ++rr) {
                int bin = (p << 6) | (wave << 3) | rr;
                int s = rptr[bin];
                int ng = (rptr[bin + 1] - s) >> 3;     // groups of 8 edges
                const uint4* sp = (const uint4*)&srec[s + 4 * hf];
                float4 a = acc[rr];
                float4 a2 = make_float4(0.f, 0.f, 0.f, 0.f);
                int g = 0;
                for (; g + 2 <= ng; g += 2) {          // 2 groups: 8 gathers
                    uint4 q0 = sp[2 * g];
                    uint4 q1 = sp[2 * g + 2];
                    uint2 u0 = hv2cl[(q0.x >> 16) << 5];
                    uint2 u1 = hv2cl[(q0.y >> 16) << 5];
                    uint2 u2 = hv2cl[(q0.z >> 16) << 5];
                    uint2 u3 = hv2cl[(q0.w >> 16) << 5];
                    uint2 u4 = hv2cl[(q1.x >> 16) << 5];
                    uint2 u5 = hv2cl[(q1.y >> 16) << 5];
                    uint2 u6 = hv2cl[(q1.z >> 16) << 5];
                    uint2 u7 = hv2cl[(q1.w >> 16) << 5];
                    float v0 = bf16lo_to_f(q0.x);
                    float v1 = bf16lo_to_f(q0.y);
                    float v2 = bf16lo_to_f(q0.z);
                    float v3 = bf16lo_to_f(q0.w);
                    float v4 = bf16lo_to_f(q1.x);
                    float v5 = bf16lo_to_f(q1.y);
                    float v6 = bf16lo_to_f(q1.z);
                    float v7 = bf16lo_to_f(q1.w);
                    a.x  += v0 * bf16lo_to_f(u0.x); a.y  += v0 * bf16hi_to_f(u0.x);
                    a.z  += v0 * bf16lo_to_f(u0.y); a.w  += v0 * bf16hi_to_f(u0.y);
                    a.x  += v1 * bf16lo_to_f(u1.x); a.y  += v1 * bf16hi_to_f(u1.x);
                    a.z  += v1 * bf16lo_to_f(u1.y); a.w  += v1 * bf16hi_to_f(u1.y);
                    a.x  += v2 * bf16lo_to_f(u2.x); a.y  += v2 * bf16hi_to_f(u2.x);
                    a.z  += v2 * bf16lo_to_f(u2.y); a.w  += v2 * bf16hi_to_f(u2.y);
                    a.x  += v3 * bf16lo_to_f(u3.x); a.y  += v3 * bf16hi_to_f(u3.x);
                    a.z  += v3 * bf16lo_to_f(u3.y); a.w  += v3 * bf16hi_to_f(u3.y);
                    a2.x += v4 * bf16lo_to_f(u4.x); a2.y += v4 * bf16hi_to_f(u4.x);
                    a2.z += v4 * bf16lo_to_f(u4.y); a2.w += v4 * bf16hi_to_f(u4.y);
                    a2.x += v5 * bf16lo_to_f(u5.x); a2.y += v5 * bf16hi_to_f(u5.x);
                    a2.z += v5 * bf16lo_to_f(u5.y); a2.w += v5 * bf16hi_to_f(u5.y);
                    a2.x += v6 * bf16lo_to_f(u6.x); a2.y += v6 * bf16hi_to_f(u6.x);
                    a2.z += v6 * bf16lo_to_f(u6.y); a2.w += v6 * bf16hi_to_f(u6.y);
                    a2.x += v7 * bf16lo_to_f(u7.x); a2.y += v7 * bf16hi_to_f(u7.x);
                    a2.z += v7 * bf16lo_to_f(u7.y); a2.w += v7 * bf16hi_to_f(u7.y);
                }
                if (g < ng) {                          // odd tail group
                    uint4 q0 = sp[2 * g];
                    uint2 u0 = hv2cl[(q0.x >> 16) << 5];
                    uint2 u1 = hv2cl[(q0.y >> 16) << 5];
                    uint2 u2 = hv2cl[(q0.z >> 16) << 5];
                    uint2 u3 = hv2cl[(q0.w >> 16) << 5];
                    float v0 = bf16lo_to_f(q0.x);
                    float v1 = bf16lo_to_f(q0.y);
                    float v2 = bf16lo_to_f(q0.z);
                    float v3 = bf16lo_to_f(q0.w);
                    a.x += v0 * bf16lo_to_f(u0.x); a.y += v0 * bf16hi_to_f(u0.x);
                    a.z += v0 * bf16lo_to_f(u0.y); a.w += v0 * bf16hi_to_f(u0.y);
                    a.x += v1 * bf16lo_to_f(u1.x); a.y += v1 * bf16hi_to_f(u1.x);
                    a.z += v1 * bf16lo_to_f(u1.y); a.w += v1 * bf16hi_to_f(u1.y);
                    a.x += v2 * bf16lo_to_f(u2.x); a.y += v2 * bf16hi_to_f(u2.x);
                    a.z += v2 * bf16lo_to_f(u2.y); a.w += v2 * bf16hi_to_f(u2.y);
                    a.x += v3 * bf16lo_to_f(u3.x); a.y += v3 * bf16hi_to_f(u3.x);
                    a.z += v3 * bf16lo_to_f(u3.y); a.w += v3 * bf16hi_to_f(u3.y);
                }
                a.x += a2.x; a.y += a2.y; a.z += a2.z; a.w += a2.w;
                acc[rr] = a;
            }
            __syncthreads();                           // phase coherence
        }
    }

    // ---- stage S = A@hV block into LDS (aliases srec; loop ended w/ barrier)
    float* Sbuf = (float*)srec;                        // [64][132] f32, 33792 B
#pragma unroll
    for (int rr = 0; rr < 8; ++rr) {
        float4 a = acc[rr];
        a.x += __shfl_xor(a.x, 32);
        a.y += __shfl_xor(a.y, 32);
        a.z += __shfl_xor(a.z, 32);
        a.w += __shfl_xor(a.w, 32);
        if (hf == 0)
            *(float4*)&Sbuf[(wave * 8 + rr) * 132 + 4 * cl] = a;
    }
    __syncthreads();

    // ---- phase 2: out = relu(x@W + S), 64x128 tile, 8 waves (4m x 2n) ----
    unsigned* xs = srec + 64 * 132;                    // u32 [64][18], 4608 B
    int wm = wave >> 1, wn = wave & 1;
    int lm = lane & 15, lk = lane >> 4;
    f32x4 acc4[4];
#pragma unroll
    for (int j = 0; j < 4; ++j) acc4[j] = (f32x4){0.f, 0.f, 0.f, 0.f};

    int r0 = b * BROWS;
    int srow = min(r0 + (t >> 3), N - 1);
    const float* xrow = x + (size_t)srow * DIN + (t & 7) * 4;
    unsigned* xsw = &xs[(t >> 3) * 18 + (t & 7) * 2];

    for (int k0 = 0; k0 < DIN; k0 += 32) {
        float4 f = *(const float4*)(xrow + k0);
        xsw[0] = pack2(f.x, f.y);
        xsw[1] = pack2(f.z, f.w);
        __syncthreads();
        FragU a;
        a.q = *(const uint4*)&xs[(wm * 16 + lm) * 18 + lk * 4];
#pragma unroll
        for (int j = 0; j < 4; ++j) {
            FragU bb;
            bb.q = *(const uint4*)(WTu + (size_t)(wn * 64 + j * 16 + lm) * 128 +
                                   (k0 >> 1) + lk * 4);
            acc4[j] = __builtin_amdgcn_mfma_f32_16x16x32_bf16(
                a.f, bb.f, acc4[j], 0, 0, 0);
        }
        __syncthreads();
    }
#pragma unroll
    for (int j = 0; j < 4; ++j) {
        int gc = wn * 64 + j * 16 + lm;
#pragma unroll
        for (int r = 0; r < 4; ++r) {
            int lr = wm * 16 + 4 * lk + r;
            int gr = r0 + lr;
            if (gr < N)
                out[(size_t)gr * DOUT + gc] =
                    fmaxf(acc4[j][r] + Sbuf[lr * 132 + gc], 0.f);
        }
    }
}

// ==================== fallback path (ws too small / N too big) =============
__global__ void spmm_atomic(const int* __restrict__ rows,
                            const int* __restrict__ cols,
                            const float* __restrict__ vals,
                            const float* __restrict__ h,
                            float* __restrict__ S, int nEdges) {
    int wave = (int)((blockIdx.x * blockDim.x + threadIdx.x) >> 6);
    int lane = threadIdx.x & 63;
    if (wave >= nEdges) return;
    int r = rows[wave], c = cols[wave];
    float v = vals[wave];
    float2 hv = ((const float2*)(h + (size_t)c * DOUT))[lane];
    float* srow = S + (size_t)r * DOUT;
    atomicAdd(srow + 2 * lane,     v * hv.x);
    atomicAdd(srow + 2 * lane + 1, v * hv.y);
}

__global__ __launch_bounds__(256) void fused_out_full(const float* __restrict__ x,
                                                      const float* __restrict__ W,
                                                      const float* __restrict__ V,
                                                      float* __restrict__ out, int N) {
    __shared__ float xs[DIN];
    __shared__ float ss[DOUT];
    int r = blockIdx.x;
    int col = threadIdx.x & 127;
    if (threadIdx.x < 128) {
        float2 xv = ((const float2*)(x + (size_t)r * DIN))[col];
        xs[2 * col] = xv.x; xs[2 * col + 1] = xv.y;
        ss[col] = out[(size_t)r * DOUT + col];
    }
    __syncthreads();
    if (threadIdx.x >= 128) return;
    float acc = 0.f;
    for (int k = 0; k < DIN; ++k) acc += xs[k] * W[k * DOUT + col];
    for (int k = 0; k < DOUT; ++k) acc += ss[k] * V[k * DOUT + col];
    out[(size_t)r * DOUT + col] = fmaxf(acc, 0.f);
}

static inline size_t align256(size_t v) { return (v + 255) & ~(size_t)255; }

extern "C" void kernel_launch(void* const* d_in, const int* in_sizes, int n_in,
                              void* d_out, int out_size, void* d_ws, size_t ws_size,
                              hipStream_t stream) {
    const float* x    = (const float*)d_in[0];
    const float* h    = (const float*)d_in[1];
    const int*   rows = (const int*)d_in[2];
    const int*   cols = (const int*)d_in[3];
    const float* vals = (const float*)d_in[4];
    const float* W    = (const float*)d_in[5];
    const float* V    = (const float*)d_in[6];
    // d_in[7] (alpha): softmax over a size-1 axis == 1 -> dead.

    int nE = in_sizes[2];              // D*E = 6.4M
    int N  = in_sizes[1] / DOUT;       // 50000
    int nb = (N + BROWS - 1) / BROWS;  // 782 buckets
    float* out = (float*)d_out;
    float regInv = (float)NREG / (float)N;

    // ws: hV[N*128 bf16] | WT[128x256 bf16] | VT[128x128 bf16] |
    //     gcnt | bptr | gcur | ecv4[nE u32] | erow[nE u8]
    size_t o_hV   = 0;
    size_t o_WT   = o_hV   + align256((size_t)N * DOUT * 2);
    size_t o_VT   = o_WT   + align256((size_t)128 * 256 * 2);
    size_t o_gcnt = o_VT   + align256((size_t)128 * 128 * 2);
    size_t o_bptr = o_gcnt + align256((size_t)nb * 4);
    size_t o_gcur = o_bptr + align256((size_t)(nb + 1) * 4);
    size_t o_ecv4 = o_gcur + align256((size_t)nb * 4);
    size_t o_erow = o_ecv4 + align256((size_t)nE * 4);
    size_t need   = o_erow + (size_t)nE;

    if (ws_size >= need && N < 65536 && nb <= MAXNB) {
        char* p = (char*)d_ws;
        unsigned short* hV = (unsigned short*)(p + o_hV);
        unsigned short* WT = (unsigned short*)(p + o_WT);
        unsigned short* VT = (unsigned short*)(p + o_VT);
        int*      gcnt = (int*)(p + o_gcnt);
        int*      bptr = (int*)(p + o_bptr);
        int*      gcur = (int*)(p + o_gcur);
        unsigned* ecv4 = (unsigned*)(p + o_ecv4);
        unsigned char* erow = (unsigned char*)(p + o_erow);

        conv_wv<<<128, 256, 0, stream>>>(W, V, WT, VT);
        hv_gemm<<<(N + 63) / 64, 256, 0, stream>>>(h, (const unsigned*)VT, hV, N);
        hipMemsetAsync(gcnt, 0, (size_t)nb * 4, stream);
        bucket_hist<<<1024, 256, 0, stream>>>(rows, gcnt, nE, nb);
        scan_buckets<<<1, 1024, 0, stream>>>(gcnt, bptr, gcur, nb);
        bin_edges<<<(nE + BIN_CHUNK - 1) / BIN_CHUNK, 1024, 0, stream>>>(
            rows, cols, vals, gcur, ecv4, erow, nE, nb, regInv);
        spmm_epi<<<nb, 512, 0, stream>>>(bptr, ecv4, erow, (const unsigned*)hV,
                                         x, (const unsigned*)WT, out, N);
    } else {
        hipMemsetAsync(out, 0, (size_t)N * DOUT * 4, stream);
        spmm_atomic<<<(nE + 3) / 4, 256, 0, stream>>>(rows, cols, vals, h, out, nE);
        fused_out_full<<<N, 128, 0, stream>>>(x, W, V, out, N);
    }
}

// Round 11
// 530.156 us; speedup vs baseline: 1.0213x; 1.0213x over previous
//
#include <hip/hip_runtime.h>
#include <hip/hip_bf16.h>

#define DOUT 128
#define DIN  256
#define BROWS 64            // rows per bucket
#define MAXNB 1024          // bucket-scan width cap (nb = ceil(N/64) = 782)
#define BIN_CHUNK 4096      // edges per bin_edges block
#define SCHUNK 9216         // edges per spmm LDS chunk (mean 8184 + 11 sigma)
#define NREG 4              // hV row regions (3.2 MB each -> per-XCD L2)
#define SBINS (NREG * BROWS)

typedef __attribute__((ext_vector_type(8))) short bf16x8;
typedef __attribute__((ext_vector_type(4))) float f32x4;
union FragU { uint4 q; bf16x8 f; };

static __device__ __forceinline__ float bf16lo_to_f(unsigned u) {
    return __uint_as_float(u << 16);
}
static __device__ __forceinline__ float bf16hi_to_f(unsigned u) {
    return __uint_as_float(u & 0xffff0000u);
}
static __device__ __forceinline__ unsigned f_to_bf16_bits(float f) {
    unsigned u = __float_as_uint(f);               // RNE round to bf16
    return (u + 0x7fffu + ((u >> 16) & 1u)) >> 16;
}
static __device__ __forceinline__ unsigned pack2(float a, float b) {
    return f_to_bf16_bits(a) | (f_to_bf16_bits(b) << 16);
}

// ========== tiny: W^T, V^T -> bf16 (done once, 96 KB total) ================
__global__ __launch_bounds__(256) void conv_wv(const float* __restrict__ W,
                                               const float* __restrict__ V,
                                               unsigned short* __restrict__ WT,
                                               unsigned short* __restrict__ VT) {
    int n = blockIdx.x;                 // 0..127 output row (= col of W/V)
    int t = threadIdx.x;                // 0..255
    WT[n * 256 + t] = (unsigned short)f_to_bf16_bits(W[t * DOUT + n]);
    if (t < 128) VT[n * 128 + t] = (unsigned short)f_to_bf16_bits(V[t * DOUT + n]);
}

// ======================= hV = h @ V via MFMA (validated r5) ================
__global__ __launch_bounds__(256) void hv_gemm(const float* __restrict__ h,
                                               const unsigned* __restrict__ VTu,
                                               unsigned short* __restrict__ hV,
                                               int N) {
    __shared__ unsigned xs[64 * 20];
    int t = threadIdx.x;
    int r0 = blockIdx.x * 64;
    int w = t >> 6, l = t & 63;
    int wm = w >> 1, wn = w & 1;
    int lm = l & 15, lk = l >> 4;
    f32x4 acc[2][4];
#pragma unroll
    for (int i = 0; i < 2; ++i)
#pragma unroll
        for (int j = 0; j < 4; ++j) acc[i][j] = (f32x4){0.f, 0.f, 0.f, 0.f};

    int srow = min(r0 + (t >> 2), N - 1);
    const float* hrow = h + (size_t)srow * DOUT + (t & 3) * 8;
    unsigned* xsw = &xs[(t >> 2) * 20 + (t & 3) * 4];

    for (int k0 = 0; k0 < DOUT; k0 += 32) {
        float4 f0 = *(const float4*)(hrow + k0);
        float4 f1 = *(const float4*)(hrow + k0 + 4);
        ((uint4*)xsw)[0] = make_uint4(pack2(f0.x, f0.y), pack2(f0.z, f0.w),
                                      pack2(f1.x, f1.y), pack2(f1.z, f1.w));
        __syncthreads();
        FragU a[2], b[4];
#pragma unroll
        for (int i = 0; i < 2; ++i)
            a[i].q = *(const uint4*)&xs[(wm * 32 + i * 16 + lm) * 20 + lk * 4];
#pragma unroll
        for (int j = 0; j < 4; ++j)
            b[j].q = *(const uint4*)(VTu + (size_t)(wn * 64 + j * 16 + lm) * 64 +
                                     (k0 >> 1) + lk * 4);
#pragma unroll
        for (int i = 0; i < 2; ++i)
#pragma unroll
            for (int j = 0; j < 4; ++j)
                acc[i][j] = __builtin_amdgcn_mfma_f32_16x16x32_bf16(
                    a[i].f, b[j].f, acc[i][j], 0, 0, 0);
        __syncthreads();
    }
#pragma unroll
    for (int i = 0; i < 2; ++i)
#pragma unroll
        for (int j = 0; j < 4; ++j) {
            int gr0 = r0 + wm * 32 + i * 16 + lk * 4;
            int gc = wn * 64 + j * 16 + lm;
#pragma unroll
            for (int r = 0; r < 4; ++r) {
                int gr = gr0 + r;
                if (gr < N)
                    hV[(size_t)gr * DOUT + gc] =
                        (unsigned short)f_to_bf16_bits(acc[i][j][r]);
            }
        }
}

// ======================= bucket histogram (validated r5) ===================
__global__ void bucket_hist(const int* __restrict__ rows, int* __restrict__ gcnt,
                            int nE, int nb) {
    __shared__ int hc[MAXNB];
    for (int i = threadIdx.x; i < nb; i += blockDim.x) hc[i] = 0;
    __syncthreads();
    for (int i = blockIdx.x * blockDim.x + threadIdx.x; i < nE;
         i += gridDim.x * blockDim.x)
        atomicAdd(&hc[rows[i] / BROWS], 1);
    __syncthreads();
    for (int i = threadIdx.x; i < nb; i += blockDim.x)
        if (hc[i]) atomicAdd(&gcnt[i], hc[i]);
}

// ============ exclusive scan of bucket counts (shfl-scan r6) ===============
__global__ __launch_bounds__(1024) void scan_buckets(const int* __restrict__ gcnt,
                                                     int* __restrict__ bptr,
                                                     int* __restrict__ gcur, int nb) {
    __shared__ int wtot[16];
    int t = threadIdx.x;
    int c = (t < nb) ? gcnt[t] : 0;
    int v = c;
#pragma unroll
    for (int d = 1; d < 64; d <<= 1) {
        int u = __shfl_up(v, d);
        if ((t & 63) >= d) v += u;
    }
    if ((t & 63) == 63) wtot[t >> 6] = v;
    __syncthreads();
    if (t < 16) {
        int wv = wtot[t];
#pragma unroll
        for (int d = 1; d < 16; d <<= 1) {
            int u = __shfl_up(wv, d);
            if (t >= d) wv += u;
        }
        wtot[t] = wv;
    }
    __syncthreads();
    int incl = v + ((t >= 64) ? wtot[(t >> 6) - 1] : 0);
    if (t == 0) bptr[0] = 0;
    if (t < nb) { bptr[t + 1] = incl; gcur[t] = incl - c; }
}

// ===== bin edges into bucket-major order (shfl-scan r6) ====================
// erow byte carries (col_region<<6) | local_row (validated r7).
__global__ __launch_bounds__(1024) void bin_edges(const int* __restrict__ rows,
                                                  const int* __restrict__ cols,
                                                  const float* __restrict__ vals,
                                                  int* __restrict__ gcur,
                                                  unsigned* __restrict__ ecv4,
                                                  unsigned char* __restrict__ erow,
                                                  int nE, int nb, float regInv) {
    __shared__ unsigned secv[BIN_CHUNK];                   // 16 KB
    __shared__ unsigned short srow16[BIN_CHUNK];           // 8 KB
    __shared__ unsigned char sreg[BIN_CHUNK];              // 4 KB
    __shared__ int hcnt[MAXNB], loff[MAXNB], lcur[MAXNB], gbase[MAXNB];
    __shared__ int wtot[16];
    int t = threadIdx.x;
    int base = blockIdx.x * BIN_CHUNK;
    int nvalid = min(BIN_CHUNK, nE - base);
    hcnt[t] = 0;
    __syncthreads();
    for (int j = t; j < nvalid; j += 1024)            // A: local hist
        atomicAdd(&hcnt[rows[base + j] / BROWS], 1);
    __syncthreads();
    int myc = hcnt[t];                                 // B: hierarchical scan
    int v = myc;
#pragma unroll
    for (int d = 1; d < 64; d <<= 1) {
        int u = __shfl_up(v, d);
        if ((t & 63) >= d) v += u;
    }
    if ((t & 63) == 63) wtot[t >> 6] = v;
    __syncthreads();
    if (t < 16) {
        int wv = wtot[t];
#pragma unroll
        for (int d = 1; d < 16; d <<= 1) {
            int u = __shfl_up(wv, d);
            if (t >= d) wv += u;
        }
        wtot[t] = wv;
    }
    __syncthreads();
    int excl = v - myc + ((t >= 64) ? wtot[(t >> 6) - 1] : 0);
    loff[t] = excl;
    lcur[t] = excl;
    if (t < nb && myc > 0) gbase[t] = atomicAdd(&gcur[t], myc);  // C: reserve
    __syncthreads();
    for (int j = t; j < nvalid; j += 1024) {          // D: place into LDS
        int i = base + j;
        unsigned r = (unsigned)rows[i];
        int col = cols[i];
        int bk = (int)r / BROWS;
        int reg = min(NREG - 1, (int)((float)col * regInv));
        int slot = atomicAdd(&lcur[bk], 1);
        secv[slot] = ((unsigned)col << 16) | f_to_bf16_bits(vals[i]);
        srow16[slot] = (unsigned short)r;
        sreg[slot] = (unsigned char)reg;
    }
    __syncthreads();
    for (int j = t; j < nvalid; j += 1024) {          // E: coalesced write-out
        unsigned r = srow16[j];
        int bk = (int)r / BROWS;
        int dst = gbase[bk] + (j - loff[bk]);
        ecv4[dst] = secv[j];
        erow[dst] = (unsigned char)((sreg[j] << 6) | (r & (BROWS - 1)));
    }
}

// ========= SPMM + fused epilogue, r11: slab phases + 8-deep MLP ============
// r7 structure (256-bin sort, 4 L2-slab phases; fetch 157 MB validated).
// Walk unrolled 2 groups/iter (8 gathers in flight, dual accumulators).
// r10 lesson (rule #20): `unroll 1` on rr made acc[rr] runtime-indexed ->
// scratch spill (WRITE 25->273 MB). Fix: FULL unroll on rr (static acc
// index, stays in registers); `unroll 1` only on p (nothing runtime-indexed
// there). Code replication = 8x of the walk body, ~half of r7's compiled
// footprint, far from r8's 32x toolchain blow-up.
__global__ __launch_bounds__(512) void spmm_epi(const int* __restrict__ bptr,
                                                const unsigned* __restrict__ ecv4,
                                                const unsigned char* __restrict__ erow,
                                                const unsigned* __restrict__ hV,
                                                const float* __restrict__ x,
                                                const unsigned* __restrict__ WTu,
                                                float* __restrict__ out, int N) {
    __shared__ __align__(16) unsigned srec[SCHUNK + SBINS * 8];  // 45056 B
    __shared__ int rcnt[SBINS], rptr[SBINS + 1], rcur[SBINS];
    int t = threadIdx.x;
    int b = blockIdx.x;
    int wave = t >> 6, lane = t & 63;
    int hf = lane >> 5;                                // half index 0/1
    int cl = lane & 31;                                // col block: 4*cl..4*cl+3
    int beg = bptr[b], end = bptr[b + 1];
    const uint2* hv2cl = (const uint2*)hV + cl;        // row stride = 32 uint2

    float4 acc[8];
#pragma unroll
    for (int j = 0; j < 8; ++j) acc[j] = make_float4(0.f, 0.f, 0.f, 0.f);

    for (int cb = beg; cb < end; cb += SCHUNK) {
        int nval = min(SCHUNK, end - cb);
        if (t < SBINS) rcnt[t] = 0;
        __syncthreads();
        for (int j = t; j < nval; j += 512)            // hist by (reg,row) bin
            atomicAdd(&rcnt[erow[cb + j]], 1);
        __syncthreads();
        if (wave == 0) {                               // 256-bin scan, 4/lane
            int b0 = 4 * lane;
            int c0 = (rcnt[b0] + 7) & ~7;
            int c1 = (rcnt[b0 + 1] + 7) & ~7;
            int c2 = (rcnt[b0 + 2] + 7) & ~7;
            int c3 = (rcnt[b0 + 3] + 7) & ~7;
            int s1 = c0 + c1, s2 = s1 + c2, tot = s2 + c3;
            int v = tot;
#pragma unroll
            for (int d = 1; d < 64; d <<= 1) {
                int u = __shfl_up(v, d);
                if (lane >= d) v += u;
            }
            int base0 = v - tot;
            rptr[b0 + 1] = base0 + c0;
            rptr[b0 + 2] = base0 + s1;
            rptr[b0 + 3] = base0 + s2;
            rptr[b0 + 4] = base0 + tot;
            rcur[b0]     = base0;
            rcur[b0 + 1] = base0 + c0;
            rcur[b0 + 2] = base0 + s1;
            rcur[b0 + 3] = base0 + s2;
            if (lane == 0) rptr[0] = 0;
        }
        __syncthreads();
        for (int j = t; j < nval; j += 512) {          // place sorted-by-bin
            int bin = erow[cb + j];
            int slot = atomicAdd(&rcur[bin], 1);
            srec[slot] = ecv4[cb + j];
        }
        __syncthreads();
        if (t < SBINS) {                               // zero-fill pad slots
            int e0 = rcur[t];
            int e1 = rptr[t + 1];
            for (int k = e0; k < e1; ++k) srec[k] = 0u;
        }
        __syncthreads();
#pragma unroll 1
        for (int p = 0; p < NREG; ++p) {               // L2-slab phases
#pragma unroll
            for (int rr = 0; rr < 8; ++rr) {           // FULL unroll: static acc
                int bin = (p << 6) | (wave << 3) | rr;
                int s = rptr[bin];
                int ng = (rptr[bin + 1] - s) >> 3;     // groups of 8 edges
                const uint4* sp = (const uint4*)&srec[s + 4 * hf];
                float4 a = acc[rr];
                float4 a2 = make_float4(0.f, 0.f, 0.f, 0.f);
                int g = 0;
                for (; g + 2 <= ng; g += 2) {          // 2 groups: 8 gathers
                    uint4 q0 = sp[2 * g];
                    uint4 q1 = sp[2 * g + 2];
                    uint2 u0 = hv2cl[(q0.x >> 16) << 5];
                    uint2 u1 = hv2cl[(q0.y >> 16) << 5];
                    uint2 u2 = hv2cl[(q0.z >> 16) << 5];
                    uint2 u3 = hv2cl[(q0.w >> 16) << 5];
                    uint2 u4 = hv2cl[(q1.x >> 16) << 5];
                    uint2 u5 = hv2cl[(q1.y >> 16) << 5];
                    uint2 u6 = hv2cl[(q1.z >> 16) << 5];
                    uint2 u7 = hv2cl[(q1.w >> 16) << 5];
                    float v0 = bf16lo_to_f(q0.x);
                    float v1 = bf16lo_to_f(q0.y);
                    float v2 = bf16lo_to_f(q0.z);
                    float v3 = bf16lo_to_f(q0.w);
                    float v4 = bf16lo_to_f(q1.x);
                    float v5 = bf16lo_to_f(q1.y);
                    float v6 = bf16lo_to_f(q1.z);
                    float v7 = bf16lo_to_f(q1.w);
                    a.x  += v0 * bf16lo_to_f(u0.x); a.y  += v0 * bf16hi_to_f(u0.x);
                    a.z  += v0 * bf16lo_to_f(u0.y); a.w  += v0 * bf16hi_to_f(u0.y);
                    a.x  += v1 * bf16lo_to_f(u1.x); a.y  += v1 * bf16hi_to_f(u1.x);
                    a.z  += v1 * bf16lo_to_f(u1.y); a.w  += v1 * bf16hi_to_f(u1.y);
                    a.x  += v2 * bf16lo_to_f(u2.x); a.y  += v2 * bf16hi_to_f(u2.x);
                    a.z  += v2 * bf16lo_to_f(u2.y); a.w  += v2 * bf16hi_to_f(u2.y);
                    a.x  += v3 * bf16lo_to_f(u3.x); a.y  += v3 * bf16hi_to_f(u3.x);
                    a.z  += v3 * bf16lo_to_f(u3.y); a.w  += v3 * bf16hi_to_f(u3.y);
                    a2.x += v4 * bf16lo_to_f(u4.x); a2.y += v4 * bf16hi_to_f(u4.x);
                    a2.z += v4 * bf16lo_to_f(u4.y); a2.w += v4 * bf16hi_to_f(u4.y);
                    a2.x += v5 * bf16lo_to_f(u5.x); a2.y += v5 * bf16hi_to_f(u5.x);
                    a2.z += v5 * bf16lo_to_f(u5.y); a2.w += v5 * bf16hi_to_f(u5.y);
                    a2.x += v6 * bf16lo_to_f(u6.x); a2.y += v6 * bf16hi_to_f(u6.x);
                    a2.z += v6 * bf16lo_to_f(u6.y); a2.w += v6 * bf16hi_to_f(u6.y);
                    a2.x += v7 * bf16lo_to_f(u7.x); a2.y += v7 * bf16hi_to_f(u7.x);
                    a2.z += v7 * bf16lo_to_f(u7.y); a2.w += v7 * bf16hi_to_f(u7.y);
                }
                if (g < ng) {                          // odd tail group
                    uint4 q0 = sp[2 * g];
                    uint2 u0 = hv2cl[(q0.x >> 16) << 5];
                    uint2 u1 = hv2cl[(q0.y >> 16) << 5];
                    uint2 u2 = hv2cl[(q0.z >> 16) << 5];
                    uint2 u3 = hv2cl[(q0.w >> 16) << 5];
                    float v0 = bf16lo_to_f(q0.x);
                    float v1 = bf16lo_to_f(q0.y);
                    float v2 = bf16lo_to_f(q0.z);
                    float v3 = bf16lo_to_f(q0.w);
                    a.x += v0 * bf16lo_to_f(u0.x); a.y += v0 * bf16hi_to_f(u0.x);
                    a.z += v0 * bf16lo_to_f(u0.y); a.w += v0 * bf16hi_to_f(u0.y);
                    a.x += v1 * bf16lo_to_f(u1.x); a.y += v1 * bf16hi_to_f(u1.x);
                    a.z += v1 * bf16lo_to_f(u1.y); a.w += v1 * bf16hi_to_f(u1.y);
                    a.x += v2 * bf16lo_to_f(u2.x); a.y += v2 * bf16hi_to_f(u2.x);
                    a.z += v2 * bf16lo_to_f(u2.y); a.w += v2 * bf16hi_to_f(u2.y);
                    a.x += v3 * bf16lo_to_f(u3.x); a.y += v3 * bf16hi_to_f(u3.x);
                    a.z += v3 * bf16lo_to_f(u3.y); a.w += v3 * bf16hi_to_f(u3.y);
                }
                a.x += a2.x; a.y += a2.y; a.z += a2.z; a.w += a2.w;
                acc[rr] = a;
            }
            __syncthreads();                           // phase coherence
        }
    }

    // ---- stage S = A@hV block into LDS (aliases srec; loop ended w/ barrier)
    float* Sbuf = (float*)srec;                        // [64][132] f32, 33792 B
#pragma unroll
    for (int rr = 0; rr < 8; ++rr) {
        float4 a = acc[rr];
        a.x += __shfl_xor(a.x, 32);
        a.y += __shfl_xor(a.y, 32);
        a.z += __shfl_xor(a.z, 32);
        a.w += __shfl_xor(a.w, 32);
        if (hf == 0)
            *(float4*)&Sbuf[(wave * 8 + rr) * 132 + 4 * cl] = a;
    }
    __syncthreads();

    // ---- phase 2: out = relu(x@W + S), 64x128 tile, 8 waves (4m x 2n) ----
    unsigned* xs = srec + 64 * 132;                    // u32 [64][18], 4608 B
    int wm = wave >> 1, wn = wave & 1;
    int lm = lane & 15, lk = lane >> 4;
    f32x4 acc4[4];
#pragma unroll
    for (int j = 0; j < 4; ++j) acc4[j] = (f32x4){0.f, 0.f, 0.f, 0.f};

    int r0 = b * BROWS;
    int srow = min(r0 + (t >> 3), N - 1);
    const float* xrow = x + (size_t)srow * DIN + (t & 7) * 4;
    unsigned* xsw = &xs[(t >> 3) * 18 + (t & 7) * 2];

    for (int k0 = 0; k0 < DIN; k0 += 32) {
        float4 f = *(const float4*)(xrow + k0);
        xsw[0] = pack2(f.x, f.y);
        xsw[1] = pack2(f.z, f.w);
        __syncthreads();
        FragU a;
        a.q = *(const uint4*)&xs[(wm * 16 + lm) * 18 + lk * 4];
#pragma unroll
        for (int j = 0; j < 4; ++j) {
            FragU bb;
            bb.q = *(const uint4*)(WTu + (size_t)(wn * 64 + j * 16 + lm) * 128 +
                                   (k0 >> 1) + lk * 4);
            acc4[j] = __builtin_amdgcn_mfma_f32_16x16x32_bf16(
                a.f, bb.f, acc4[j], 0, 0, 0);
        }
        __syncthreads();
    }
#pragma unroll
    for (int j = 0; j < 4; ++j) {
        int gc = wn * 64 + j * 16 + lm;
#pragma unroll
        for (int r = 0; r < 4; ++r) {
            int lr = wm * 16 + 4 * lk + r;
            int gr = r0 + lr;
            if (gr < N)
                out[(size_t)gr * DOUT + gc] =
                    fmaxf(acc4[j][r] + Sbuf[lr * 132 + gc], 0.f);
        }
    }
}

// ==================== fallback path (ws too small / N too big) =============
__global__ void spmm_atomic(const int* __restrict__ rows,
                            const int* __restrict__ cols,
                            const float* __restrict__ vals,
                            const float* __restrict__ h,
                            float* __restrict__ S, int nEdges) {
    int wave = (int)((blockIdx.x * blockDim.x + threadIdx.x) >> 6);
    int lane = threadIdx.x & 63;
    if (wave >= nEdges) return;
    int r = rows[wave], c = cols[wave];
    float v = vals[wave];
    float2 hv = ((const float2*)(h + (size_t)c * DOUT))[lane];
    float* srow = S + (size_t)r * DOUT;
    atomicAdd(srow + 2 * lane,     v * hv.x);
    atomicAdd(srow + 2 * lane + 1, v * hv.y);
}

__global__ __launch_bounds__(256) void fused_out_full(const float* __restrict__ x,
                                                      const float* __restrict__ W,
                                                      const float* __restrict__ V,
                                                      float* __restrict__ out, int N) {
    __shared__ float xs[DIN];
    __shared__ float ss[DOUT];
    int r = blockIdx.x;
    int col = threadIdx.x & 127;
    if (threadIdx.x < 128) {
        float2 xv = ((const float2*)(x + (size_t)r * DIN))[col];
        xs[2 * col] = xv.x; xs[2 * col + 1] = xv.y;
        ss[col] = out[(size_t)r * DOUT + col];
    }
    __syncthreads();
    if (threadIdx.x >= 128) return;
    float acc = 0.f;
    for (int k = 0; k < DIN; ++k) acc += xs[k] * W[k * DOUT + col];
    for (int k = 0; k < DOUT; ++k) acc += ss[k] * V[k * DOUT + col];
    out[(size_t)r * DOUT + col] = fmaxf(acc, 0.f);
}

static inline size_t align256(size_t v) { return (v + 255) & ~(size_t)255; }

extern "C" void kernel_launch(void* const* d_in, const int* in_sizes, int n_in,
                              void* d_out, int out_size, void* d_ws, size_t ws_size,
                              hipStream_t stream) {
    const float* x    = (const float*)d_in[0];
    const float* h    = (const float*)d_in[1];
    const int*   rows = (const int*)d_in[2];
    const int*   cols = (const int*)d_in[3];
    const float* vals = (const float*)d_in[4];
    const float* W    = (const float*)d_in[5];
    const float* V    = (const float*)d_in[6];
    // d_in[7] (alpha): softmax over a size-1 axis == 1 -> dead.

    int nE = in_sizes[2];              // D*E = 6.4M
    int N  = in_sizes[1] / DOUT;       // 50000
    int nb = (N + BROWS - 1) / BROWS;  // 782 buckets
    float* out = (float*)d_out;
    float regInv = (float)NREG / (float)N;

    // ws: hV[N*128 bf16] | WT[128x256 bf16] | VT[128x128 bf16] |
    //     gcnt | bptr | gcur | ecv4[nE u32] | erow[nE u8]
    size_t o_hV   = 0;
    size_t o_WT   = o_hV   + align256((size_t)N * DOUT * 2);
    size_t o_VT   = o_WT   + align256((size_t)128 * 256 * 2);
    size_t o_gcnt = o_VT   + align256((size_t)128 * 128 * 2);
    size_t o_bptr = o_gcnt + align256((size_t)nb * 4);
    size_t o_gcur = o_bptr + align256((size_t)(nb + 1) * 4);
    size_t o_ecv4 = o_gcur + align256((size_t)nb * 4);
    size_t o_erow = o_ecv4 + align256((size_t)nE * 4);
    size_t need   = o_erow + (size_t)nE;

    if (ws_size >= need && N < 65536 && nb <= MAXNB) {
        char* p = (char*)d_ws;
        unsigned short* hV = (unsigned short*)(p + o_hV);
        unsigned short* WT = (unsigned short*)(p + o_WT);
        unsigned short* VT = (unsigned short*)(p + o_VT);
        int*      gcnt = (int*)(p + o_gcnt);
        int*      bptr = (int*)(p + o_bptr);
        int*      gcur = (int*)(p + o_gcur);
        unsigned* ecv4 = (unsigned*)(p + o_ecv4);
        unsigned char* erow = (unsigned char*)(p + o_erow);

        conv_wv<<<128, 256, 0, stream>>>(W, V, WT, VT);
        hv_gemm<<<(N + 63) / 64, 256, 0, stream>>>(h, (const unsigned*)VT, hV, N);
        hipMemsetAsync(gcnt, 0, (size_t)nb * 4, stream);
        bucket_hist<<<1024, 256, 0, stream>>>(rows, gcnt, nE, nb);
        scan_buckets<<<1, 1024, 0, stream>>>(gcnt, bptr, gcur, nb);
        bin_edges<<<(nE + BIN_CHUNK - 1) / BIN_CHUNK, 1024, 0, stream>>>(
            rows, cols, vals, gcur, ecv4, erow, nE, nb, regInv);
        spmm_epi<<<nb, 512, 0, stream>>>(bptr, ecv4, erow, (const unsigned*)hV,
                                         x, (const unsigned*)WT, out, N);
    } else {
        hipMemsetAsync(out, 0, (size_t)N * DOUT * 4, stream);
        spmm_atomic<<<(nE + 3) / 4, 256, 0, stream>>>(rows, cols, vals, h, out, nE);
        fused_out_full<<<N, 128, 0, stream>>>(x, W, V, out, N);
    }
}